// Round 6
// baseline (134.449 us; speedup 1.0000x reference)
//
#include <hip/hip_runtime.h>

// EuclideanCodebook: fp16 MFMA approx distance (A staged once in swizzled LDS,
// B streamed from L2) + top-2 margin flag + split-K exact fp32 rescue.
// x: [N=32768][256] f32, embedding_sum: [K=2048][256] f32, usage: [K] f32
// out: quantized [N*256] f32, codes [N] f32

#define EPSV 1e-5f
#define DDIM 256
#define TAU  0.4f
#define BM   64      // rows per block (vq_mfma)
#define BCL  128     // clusters per tile
#define RPB  8       // rescue rows per group
#define KSPL 4       // rescue K split

typedef __attribute__((ext_vector_type(8))) _Float16 f16x8;
typedef __attribute__((ext_vector_type(4))) float f32x4;
typedef unsigned short u16;
typedef unsigned long long u64;

__device__ __forceinline__ u16 f2h(float f) {
    f = fminf(fmaxf(f, -60000.f), 60000.f);   // keep fp16 finite
    const _Float16 h = (_Float16)f;
    return __builtin_bit_cast(u16, h);
}
__device__ __forceinline__ u64 packdk(float d, int k) {
    unsigned u = __builtin_bit_cast(unsigned, d);
    u = (u & 0x80000000u) ? ~u : (u | 0x80000000u);   // sortable float
    return ((u64)u << 32) | (unsigned)k;
}

// ---------------- prep_e: emb, emb_t, e fp16, ||e||^2; zero counter ---------
__global__ void prep_e(const float* __restrict__ esum,
                       const float* __restrict__ usage,
                       float* __restrict__ emb,     // [K][256] f32
                       float* __restrict__ emb_t,   // [256][K] f32
                       u16* __restrict__ eh,        // [K][256] f16 bits
                       float* __restrict__ enorm2,  // [K]
                       int* __restrict__ counter,
                       int K) {
    if (blockIdx.x == 0 && threadIdx.x == 0) *counter = 0;
    const int k = blockIdx.x;
    const int d = threadIdx.x;                 // 256 threads
    const float u = fmaxf(usage[k], EPSV);
    const float e = esum[k * DDIM + d] / u;
    emb[k * DDIM + d] = e;
    emb_t[(size_t)d * K + k] = e;
    eh[k * DDIM + d] = f2h(e);

    float s = e * e;
    #pragma unroll
    for (int off = 32; off > 0; off >>= 1) s += __shfl_down(s, off, 64);
    __shared__ float ws[4];
    if ((threadIdx.x & 63) == 0) ws[threadIdx.x >> 6] = s;
    __syncthreads();
    if (threadIdx.x == 0) enorm2[k] = ws[0] + ws[1] + ws[2] + ws[3];
}

// ---------------- prep_x: x fp16 --------------------------------------------
__global__ void prep_x(const float* __restrict__ x, u16* __restrict__ xh) {
    const int n = blockIdx.x * 4 + (threadIdx.x >> 6);
    const int l = threadIdx.x & 63;
    const float4 v = *(const float4*)&x[(size_t)n * DDIM + l * 4];
    ushort4 h;
    h.x = f2h(v.x); h.y = f2h(v.y); h.z = f2h(v.z); h.w = f2h(v.w);
    *(ushort4*)&xh[(size_t)n * DDIM + l * 4] = h;
}

// ---------------- main: fp16 MFMA distance, A-resident, B from L2 -----------
// Block: 64 rows x K=2048. 4 waves = 4 cluster-columns of 32 within each
// 128-cluster tile. A in LDS (swizzled, staged once); B frags global->VGPR.
__global__ __launch_bounds__(256, 2) void vq_mfma(
        const u16* __restrict__ xh, const u16* __restrict__ eh,
        const float* __restrict__ enorm2,
        float* __restrict__ codes_f, int* __restrict__ codes_i,
        int* __restrict__ list, int* __restrict__ counter,
        u64* __restrict__ packed, int K) {
    __shared__ __align__(16) char Als[BM * 512];   // 32 KB, [64 rows][32 chunks of 16B]

    const int tid = threadIdx.x;
    const int l   = tid & 63;
    const int w   = tid >> 6;            // wave 0..3 == cluster column wc
    const int n0  = blockIdx.x * BM;

    // ---- stage A once: linear LDS dest, inverse-swizzled global source ----
    // LDS[row][c] holds global chunk (c ^ (row&7)).
    #pragma unroll
    for (int i = 0; i < 8; ++i) {
        const int rel = w * 16 + i * 2 + (l >> 5);       // row 0..63
        const int gc  = (l & 31) ^ (rel & 7);            // source chunk
        const u16* ga = xh + (size_t)(n0 + rel) * DDIM + gc * 8;
        __builtin_amdgcn_global_load_lds(
            (const __attribute__((address_space(1))) void*)ga,
            (__attribute__((address_space(3))) void*)(Als + w * 8192 + i * 1024),
            16, 0, 0);
    }
    __syncthreads();                     // only barrier before epilogue

    float m1[4][4], m2[4][4];
    int   i1[4][4];
    #pragma unroll
    for (int a = 0; a < 4; ++a)
        #pragma unroll
        for (int b = 0; b < 4; ++b) { m1[a][b] = 3.0e38f; m2[a][b] = 3.0e38f; i1[a][b] = 0; }

    for (int ct = 0; ct < K / BCL; ++ct) {
        const int c0 = ct * BCL;
        f32x4 acc[4][2];
        #pragma unroll
        for (int a = 0; a < 4; ++a) { acc[a][0] = (f32x4){0,0,0,0}; acc[a][1] = (f32x4){0,0,0,0}; }

        const u16* b0 = eh + (size_t)(c0 + w * 32 + (l & 15)) * DDIM + (l >> 4) * 8;
        #pragma unroll
        for (int ks = 0; ks < 8; ++ks) {
            f16x8 bfr[2], af[4];
            bfr[0] = *(const f16x8*)(b0 + ks * 32);
            bfr[1] = *(const f16x8*)(b0 + 16 * DDIM + ks * 32);
            #pragma unroll
            for (int f = 0; f < 4; ++f) {
                const int arow  = f * 16 + (l & 15);
                const int chunk = (ks * 4 + (l >> 4)) ^ (l & 7);   // swizzled read
                af[f] = *(const f16x8*)(Als + arow * 512 + chunk * 16);
            }
            #pragma unroll
            for (int fm = 0; fm < 4; ++fm) {
                acc[fm][0] = __builtin_amdgcn_mfma_f32_16x16x32_f16(af[fm], bfr[0], acc[fm][0], 0, 0, 0);
                acc[fm][1] = __builtin_amdgcn_mfma_f32_16x16x32_f16(af[fm], bfr[1], acc[fm][1], 0, 0, 0);
            }
        }

        // fold into running (min1, idx, min2); k ascending
        #pragma unroll
        for (int fn = 0; fn < 2; ++fn) {
            const int k = c0 + w * 32 + fn * 16 + (l & 15);
            const float en = enorm2[k];
            #pragma unroll
            for (int fm = 0; fm < 4; ++fm)
                #pragma unroll
                for (int i = 0; i < 4; ++i) {
                    const float s = fmaf(-2.0f, acc[fm][fn][i], en);
                    const bool lt1 = s < m1[fm][i];
                    m2[fm][i] = fminf(m2[fm][i], fmaxf(s, m1[fm][i]));
                    i1[fm][i] = lt1 ? k : i1[fm][i];
                    m1[fm][i] = fminf(m1[fm][i], s);
                }
        }
    }

    // reduce across the 16 lanes (l&15) sharing each row; ties -> smaller k
    #pragma unroll
    for (int fm = 0; fm < 4; ++fm)
        #pragma unroll
        for (int i = 0; i < 4; ++i) {
            float a1 = m1[fm][i], a2 = m2[fm][i];
            int ai = i1[fm][i];
            #pragma unroll
            for (int mask = 1; mask < 16; mask <<= 1) {
                const float b1 = __shfl_xor(a1, mask, 64);
                const int   bi = __shfl_xor(ai, mask, 64);
                const float b2 = __shfl_xor(a2, mask, 64);
                if (b1 < a1 || (b1 == a1 && bi < ai)) {
                    a2 = fminf(a1, fminf(a2, b2)); a1 = b1; ai = bi;
                } else {
                    a2 = fminf(b1, fminf(a2, b2));
                }
            }
            m1[fm][i] = a1; i1[fm][i] = ai; m2[fm][i] = a2;
        }

    // merge the 4 wave-columns via LDS; write codes + flags directly
    __syncthreads();                     // everyone done with A reads
    float* Sm1 = (float*)Als;                          // [4][64]
    int*   Si1 = (int*)(Als + 1024);                   // [4][64]
    float* Sm2 = (float*)(Als + 2048);                 // [4][64]
    if ((l & 15) == 0) {
        #pragma unroll
        for (int fm = 0; fm < 4; ++fm)
            #pragma unroll
            for (int i = 0; i < 4; ++i) {
                const int r = fm * 16 + (l >> 4) * 4 + i;
                Sm1[w * 64 + r] = m1[fm][i];
                Si1[w * 64 + r] = i1[fm][i];
                Sm2[w * 64 + r] = m2[fm][i];
            }
    }
    __syncthreads();
    if (tid < BM) {
        const int r = tid;
        float M1 = Sm1[r], M2 = Sm2[r];
        int   MI = Si1[r];
        #pragma unroll
        for (int j = 1; j < 4; ++j) {
            const float b1 = Sm1[j * 64 + r], b2 = Sm2[j * 64 + r];
            const int   bi = Si1[j * 64 + r];
            if (b1 < M1 || (b1 == M1 && bi < MI)) {
                M2 = fminf(M1, fminf(M2, b2)); M1 = b1; MI = bi;
            } else {
                M2 = fminf(b1, fminf(M2, b2));
            }
        }
        const int n = n0 + r;
        codes_i[n] = MI;
        codes_f[n] = (float)MI;
        if (M2 - M1 < TAU) {
            packed[n] = 0xFFFFFFFFFFFFFFFFull;
            const int idx = atomicAdd(counter, 1);
            list[idx] = n;
        }
    }
}

// ---------------- rescue_c: exact fp32, 8 rows x 512-cluster work items -----
__global__ __launch_bounds__(256) void rescue_c(
        const float* __restrict__ x, const float* __restrict__ emb_t,
        const float* __restrict__ enorm2,
        const int* __restrict__ list, const int* __restrict__ counter,
        u64* __restrict__ packed, int K) {
    __shared__ float xs[RPB][DDIM];   // 8 KB
    const int t = threadIdx.x;
    const int l = t & 63;
    const int cnt = *counter;
    if (cnt == 0) return;
    const int nblk  = (cnt + RPB - 1) / RPB;
    const int items = nblk * KSPL;
    const int kc    = K / KSPL;       // 512

    for (int wi = blockIdx.x; wi < items; wi += gridDim.x) {
        const int g = wi >> 2;        // KSPL = 4
        const int q = wi & 3;
        const int base = g * RPB;
        int rows[RPB];
        #pragma unroll
        for (int r = 0; r < RPB; ++r) {
            int idx = base + r;
            rows[r] = list[idx < cnt ? idx : cnt - 1];
        }
        __syncthreads();              // previous iteration done reading xs
        #pragma unroll
        for (int r = 0; r < RPB; ++r)
            xs[r][t] = x[(size_t)rows[r] * DDIM + t];
        __syncthreads();

        float acc[RPB][2];
        #pragma unroll
        for (int r = 0; r < RPB; ++r) { acc[r][0] = 0.f; acc[r][1] = 0.f; }

        const float* eb = emb_t + q * kc + 2 * t;
        #pragma unroll 4
        for (int d = 0; d < DDIM; ++d) {
            const float2 e = *(const float2*)&eb[(size_t)d * K];
            #pragma unroll
            for (int r = 0; r < RPB; ++r) {
                const float xv = xs[r][d];
                acc[r][0] = fmaf(xv, e.x, acc[r][0]);
                acc[r][1] = fmaf(xv, e.y, acc[r][1]);
            }
        }

        const int k0 = q * kc + 2 * t;
        const float en0 = enorm2[k0], en1 = enorm2[k0 + 1];
        #pragma unroll
        for (int r = 0; r < RPB; ++r) {
            const float s0 = fmaf(-2.0f, acc[r][0], en0);
            const float s1 = fmaf(-2.0f, acc[r][1], en1);
            float bd = s0; int bk = k0;
            if (s1 < bd) { bd = s1; bk = k0 + 1; }
            #pragma unroll
            for (int m = 1; m < 64; m <<= 1) {
                const float od = __shfl_xor(bd, m, 64);
                const int   ok = __shfl_xor(bk, m, 64);
                if (od < bd || (od == bd && ok < bk)) { bd = od; bk = ok; }
            }
            if (l == 0) atomicMin(&packed[rows[r]], packdk(bd, bk));
        }
    }
}

// ---------------- fixup: unpack rescue winners into codes -------------------
__global__ void fixup(const u64* __restrict__ packed,
                      const int* __restrict__ list, const int* __restrict__ counter,
                      float* __restrict__ codes_f, int* __restrict__ codes_i) {
    const int i = blockIdx.x * 256 + threadIdx.x;
    if (i < *counter) {
        const int n = list[i];
        const int k = (int)(packed[n] & 0xFFFFFFFFull);
        codes_i[n] = k;
        codes_f[n] = (float)k;
    }
}

// ---------------- gather: quantized[n] = emb[code[n]] -----------------------
__global__ void gather_q(const float* __restrict__ emb,
                         const int* __restrict__ codes,
                         float* __restrict__ qout) {
    const int n = blockIdx.x * 4 + (threadIdx.x >> 6);
    const int c = threadIdx.x & 63;
    const int k = codes[n];
    *(float4*)&qout[(size_t)n * DDIM + c * 4] =
        *(const float4*)&emb[(size_t)k * DDIM + c * 4];
}

extern "C" void kernel_launch(void* const* d_in, const int* in_sizes, int n_in,
                              void* d_out, int out_size, void* d_ws, size_t ws_size,
                              hipStream_t stream) {
    const float* x     = (const float*)d_in[0];
    const float* esum  = (const float*)d_in[1];
    const float* usage = (const float*)d_in[2];
    const int K = in_sizes[2];                 // 2048
    const int N = in_sizes[0] / DDIM;          // 32768

    // workspace layout (packed first: 8B alignment)
    char* p = (char*)d_ws;
    u64*   packed  = (u64*)p;                  p += (size_t)N * 8;          // 256 KB
    float* emb     = (float*)p;                p += (size_t)K * DDIM * 4;   // 2 MB
    float* emb_t   = (float*)p;                p += (size_t)K * DDIM * 4;   // 2 MB
    float* enorm2  = (float*)p;                p += (size_t)K * 4;
    int*   codes_i = (int*)p;                  p += (size_t)N * 4;
    int*   list    = (int*)p;                  p += (size_t)N * 4;
    int*   counter = (int*)p;                  p += 256;
    u16*   xh      = (u16*)p;                  p += (size_t)N * DDIM * 2;   // 16 MB
    u16*   eh      = (u16*)p;                  p += (size_t)K * DDIM * 2;   // 1 MB

    float* qout    = (float*)d_out;            // N*256
    float* codes_f = qout + (size_t)N * DDIM;  // N

    prep_e<<<K, 256, 0, stream>>>(esum, usage, emb, emb_t, eh, enorm2, counter, K);
    prep_x<<<N / 4, 256, 0, stream>>>(x, xh);
    vq_mfma<<<N / BM, 256, 0, stream>>>(xh, eh, enorm2, codes_f, codes_i,
                                        list, counter, packed, K);
    rescue_c<<<1024, 256, 0, stream>>>(x, emb_t, enorm2, list, counter, packed, K);
    fixup<<<N / 256, 256, 0, stream>>>(packed, list, counter, codes_f, codes_i);
    gather_q<<<N / 4, 256, 0, stream>>>(emb, codes_i, qout);
}